// Round 6
// baseline (204.952 us; speedup 1.0000x reference)
//
#include <hip/hip_runtime.h>
#include <math.h>
#include <stdint.h>

// Problem constants (from reference setup_inputs)
constexpr int NB  = 16;          // batches
constexpr int XY  = 512 * 512;   // pixels per image
constexpr int NV  = XY / 4;      // float4 vectors per plane per batch (65536)

constexpr int G1   = 32;         // blocks per batch -> 512 blocks = exactly 2/CU
constexpr int WIN  = 256;        // float4 vecs per window per plane (4 KB)
constexpr int NWIN = NV / (G1 * WIN);   // 8 windows per block (compile-time)
constexpr int BUFB = 8 * 4096;   // bytes per LDS buffer (8 planes x 4 KB)

// Workspace layout (every location written before read => no memset, no atomics,
// poison-safe):
//   bytes [0 .. 4095]  : double tot[NB][32]      (29 used; reduce_totals)
//   bytes [P1OFF ..]   : float  p1[NB][G1][32]   (29 used; pass1 moments)
//   bytes [P2OFF ..]   : float  p2[NB][G1]       (pass2 loglik partials)
constexpr int P1OFF = 4096;
constexpr int P2OFF = P1OFF + NB * G1 * 32 * 4;   // 69632

__device__ __forceinline__ float waveReduce64(float v) {
#pragma unroll
    for (int off = 32; off > 0; off >>= 1) v += __shfl_down(v, off, 64);
    return v;
}

// Coerce a block-uniform float into an SGPR.
__device__ __forceinline__ float rfl(float x) {
    return __uint_as_float(__builtin_amdgcn_readfirstlane(__float_as_uint(x)));
}

// Async global->LDS DMA, 16 B per lane. LDS dest is wave-uniform base + lane*16;
// global src is per-lane. Zero VGPRs consumed for data.
__device__ __forceinline__ void gl2lds(const void* g, void* l) {
    __builtin_amdgcn_global_load_lds(
        (__attribute__((address_space(1))) void*)(void*)g,
        (__attribute__((address_space(3))) void*)l,
        16, 0, 0);
}

// Counted vmcnt waits (m218 discipline: never drain to 0 mid-loop). The
// sched_barrier after each wait keeps the compiler from hoisting ds_reads
// above it (rule #18).
#define VMWAIT8  do { asm volatile("s_waitcnt vmcnt(8)" ::: "memory"); \
                      __builtin_amdgcn_sched_barrier(0); } while (0)
#define VMWAIT0  do { asm volatile("s_waitcnt vmcnt(0)" ::: "memory"); \
                      __builtin_amdgcn_sched_barrier(0); } while (0)

// Straight-line per-pixel moment accumulation (29 named scalar accumulators).
#define PIX1(h_, e0_, e1_, e2_, p0_, p1_, p2_, p3_) do {                      \
    float mm_ = ((h_) == 1) ? 1.f : 0.f;                                      \
    cnt += mm_;                                                               \
    float w0_ = (p0_) * mm_, w1_ = (p1_) * mm_, w2_ = (p2_) * mm_,            \
          w3_ = (p3_) * mm_;                                                  \
    s0_0 += w0_; s0_1 += w1_; s0_2 += w2_; s0_3 += w3_;                       \
    float t_;                                                                 \
    t_ = w0_ * (e0_); u00 += t_; q00 = fmaf(t_, (e0_), q00);                  \
    t_ = w0_ * (e1_); u01 += t_; q01 = fmaf(t_, (e1_), q01);                  \
    t_ = w0_ * (e2_); u02 += t_; q02 = fmaf(t_, (e2_), q02);                  \
    t_ = w1_ * (e0_); u10 += t_; q10 = fmaf(t_, (e0_), q10);                  \
    t_ = w1_ * (e1_); u11 += t_; q11 = fmaf(t_, (e1_), q11);                  \
    t_ = w1_ * (e2_); u12 += t_; q12 = fmaf(t_, (e2_), q12);                  \
    t_ = w2_ * (e0_); u20 += t_; q20 = fmaf(t_, (e0_), q20);                  \
    t_ = w2_ * (e1_); u21 += t_; q21 = fmaf(t_, (e1_), q21);                  \
    t_ = w2_ * (e2_); u22 += t_; q22 = fmaf(t_, (e2_), q22);                  \
    t_ = w3_ * (e0_); u30 += t_; q30 = fmaf(t_, (e0_), q30);                  \
    t_ = w3_ * (e1_); u31 += t_; q31 = fmaf(t_, (e1_), q31);                  \
    t_ = w3_ * (e2_); u32 += t_; q32 = fmaf(t_, (e2_), q32);                  \
} while (0)

// Per-component parameter reconstruction (block-uniform, f64 for the
// cancellation in S2 - 2 mu S1 + mu^2 S0).
#define PARAMK(K_, mu0_, mu1_, mu2_, h0_, h1_, h2_, C_) {                     \
    double S0_ = tot[1 + (K_)];                                               \
    double den_ = S0_ + 1e-10;                                                \
    double Cd_ = 1.0;                                                         \
    double S1_, S2_, muv_, var_;                                              \
    S1_ = tot[5 + (K_)*3 + 0]; S2_ = tot[17 + (K_)*3 + 0];                    \
    muv_ = S1_ / den_;                                                        \
    var_ = (S2_ - 2.0 * muv_ * S1_ + muv_ * muv_ * S0_) / den_ + 1e-10;       \
    mu0_ = (float)muv_; h0_ = (float)(0.5 / var_);                            \
    Cd_ *= 1.0 / sqrt(6.283185307179586 * var_);                              \
    S1_ = tot[5 + (K_)*3 + 1]; S2_ = tot[17 + (K_)*3 + 1];                    \
    muv_ = S1_ / den_;                                                        \
    var_ = (S2_ - 2.0 * muv_ * S1_ + muv_ * muv_ * S0_) / den_ + 1e-10;       \
    mu1_ = (float)muv_; h1_ = (float)(0.5 / var_);                            \
    Cd_ *= 1.0 / sqrt(6.283185307179586 * var_);                              \
    S1_ = tot[5 + (K_)*3 + 2]; S2_ = tot[17 + (K_)*3 + 2];                    \
    muv_ = S1_ / den_;                                                        \
    var_ = (S2_ - 2.0 * muv_ * S1_ + muv_ * muv_ * S0_) / den_ + 1e-10;       \
    mu2_ = (float)muv_; h2_ = (float)(0.5 / var_);                            \
    Cd_ *= 1.0 / sqrt(6.283185307179586 * var_);                              \
    C_ = (float)Cd_;                                                          \
}

#define PIX2(h_, e0_, e1_, e2_, p0_, p1_, p2_, p3_) do {                      \
    float m_ = ((h_) == 1) ? 1.f : 0.f;                                       \
    float d0_, d1_, d2_, ex_, pc_;                                            \
    float mix_;                                                               \
    d0_ = (e0_) - mu00; d1_ = (e1_) - mu01; d2_ = (e2_) - mu02;               \
    ex_ = fmaf(d0_ * d0_, hv00, fmaf(d1_ * d1_, hv01, d2_ * d2_ * hv02));     \
    pc_ = (p0_) * (p0_) * (p0_);                                              \
    mix_ = C0 * pc_ * __expf(-ex_);                                           \
    d0_ = (e0_) - mu10; d1_ = (e1_) - mu11; d2_ = (e2_) - mu12;               \
    ex_ = fmaf(d0_ * d0_, hv10, fmaf(d1_ * d1_, hv11, d2_ * d2_ * hv12));     \
    pc_ = (p1_) * (p1_) * (p1_);                                              \
    mix_ = fmaf(C1 * pc_, __expf(-ex_), mix_);                                \
    d0_ = (e0_) - mu20; d1_ = (e1_) - mu21; d2_ = (e2_) - mu22;               \
    ex_ = fmaf(d0_ * d0_, hv20, fmaf(d1_ * d1_, hv21, d2_ * d2_ * hv22));     \
    pc_ = (p2_) * (p2_) * (p2_);                                              \
    mix_ = fmaf(C2 * pc_, __expf(-ex_), mix_);                                \
    d0_ = (e0_) - mu30; d1_ = (e1_) - mu31; d2_ = (e2_) - mu32;               \
    ex_ = fmaf(d0_ * d0_, hv30, fmaf(d1_ * d1_, hv31, d2_ * d2_ * hv32));     \
    pc_ = (p3_) * (p3_) * (p3_);                                              \
    mix_ = fmaf(C3 * pc_, __expf(-ex_), mix_);                                \
    lacc += m_ * __logf(mix_ + 1e-10f);                                       \
} while (0)

// Linear per-wave streaming: wave `wav` owns plane wav (H/I0/I1/I2) and plane
// wav+4 (P1..P4). Its global reads are perfectly sequential 32 KB streams —
// the copy-bench access pattern. gA/gB already include slab + lane*16.
#define STAGE(B_, W_) do {                                                    \
    const size_t go_ = (size_t)(W_) * 4096;                                   \
    char* dA_ = lds + (B_) * BUFB + wav * 4096;                               \
    char* dB_ = dA_ + 4 * 4096;                                               \
    gl2lds(gA + go_ +    0, dA_ +    0);                                      \
    gl2lds(gA + go_ + 1024, dA_ + 1024);                                      \
    gl2lds(gA + go_ + 2048, dA_ + 2048);                                      \
    gl2lds(gA + go_ + 3072, dA_ + 3072);                                      \
    gl2lds(gB + go_ +    0, dB_ +    0);                                      \
    gl2lds(gB + go_ + 1024, dB_ + 1024);                                      \
    gl2lds(gB + go_ + 2048, dB_ + 2048);                                      \
    gl2lds(gB + go_ + 3072, dB_ + 3072);                                      \
} while (0)

// Load this thread's 8 staged vectors (one window) from LDS buffer B_.
#define LOADREGS(B_)                                                          \
    const char* cb_ = lds + (B_) * BUFB;                                      \
    int4   h  = *(const int4*)  (cb_ + 0 * 4096 + tid * 16);                  \
    float4 f0 = *(const float4*)(cb_ + 1 * 4096 + tid * 16);                  \
    float4 f1 = *(const float4*)(cb_ + 2 * 4096 + tid * 16);                  \
    float4 f2 = *(const float4*)(cb_ + 3 * 4096 + tid * 16);                  \
    float4 g0 = *(const float4*)(cb_ + 4 * 4096 + tid * 16);                  \
    float4 g1 = *(const float4*)(cb_ + 5 * 4096 + tid * 16);                  \
    float4 g2 = *(const float4*)(cb_ + 6 * 4096 + tid * 16);                  \
    float4 g3 = *(const float4*)(cb_ + 7 * 4096 + tid * 16);

// Per-wave linear global source pointers (slab of this block + lane offset).
#define DECL_GSRC                                                             \
    const size_t slab_ = (size_t)g * (NWIN * WIN) * 16 + (size_t)lane * 16;   \
    const char* gA = (wav == 0)                                               \
        ? (const char*)heart + (size_t)b * XY * 4 + slab_                     \
        : (const char*)inputs + ((size_t)b * 3 + (wav - 1)) * XY * 4 + slab_; \
    const char* gB = (const char*)predictions                                 \
        + ((size_t)b * 5 + (wav + 1)) * XY * 4 + slab_;

// Streaming pipeline shared by both passes: 2-window prefetch depth, counted
// vmcnt(8), raw s_barrier (no __syncthreads => no vmcnt(0) drain in the loop).
#define STREAM_LOOP(PIXSET_)                                                  \
    STAGE(0, 0);                                                              \
    STAGE(1, 1);                                                              \
    _Pragma("unroll")                                                         \
    for (int w = 0; w < NWIN; ++w) {                                          \
        if (w < NWIN - 1) { VMWAIT8; } else { VMWAIT0; }                      \
        __builtin_amdgcn_s_barrier();   /* window w fully staged (all waves) */\
        LOADREGS(w & 1);                                                      \
        PIXSET_;                                                              \
        __builtin_amdgcn_s_barrier();   /* all waves done reading buf w&1   */\
        if (w + 2 < NWIN) STAGE(w & 1, w + 2);                                \
    }

// ---------------------------------------------------------------------------
// Pass 1: copy-pattern streaming (linear per-wave DMA) + moments from LDS.
// ---------------------------------------------------------------------------
__global__ __launch_bounds__(256) void pass1_moments(
        const float* __restrict__ predictions,
        const float* __restrict__ inputs,
        const int*   __restrict__ heart,
        char*        __restrict__ wsraw) {
    const int b    = blockIdx.y;
    const int g    = blockIdx.x;
    const int tid  = threadIdx.x;
    const int lane = tid & 63;
    const int wav  = tid >> 6;

    __shared__ __align__(16) char lds[2 * BUFB];   // 64 KB double buffer
    __shared__ float shred[4][32];

    DECL_GSRC;

    float cnt = 0.f;
    float s0_0 = 0.f, s0_1 = 0.f, s0_2 = 0.f, s0_3 = 0.f;
    float u00 = 0.f, u01 = 0.f, u02 = 0.f, u10 = 0.f, u11 = 0.f, u12 = 0.f;
    float u20 = 0.f, u21 = 0.f, u22 = 0.f, u30 = 0.f, u31 = 0.f, u32 = 0.f;
    float q00 = 0.f, q01 = 0.f, q02 = 0.f, q10 = 0.f, q11 = 0.f, q12 = 0.f;
    float q20 = 0.f, q21 = 0.f, q22 = 0.f, q30 = 0.f, q31 = 0.f, q32 = 0.f;

#define PIXSET1_                                                              \
    PIX1(h.x, f0.x, f1.x, f2.x, g0.x, g1.x, g2.x, g3.x);                      \
    PIX1(h.y, f0.y, f1.y, f2.y, g0.y, g1.y, g2.y, g3.y);                      \
    PIX1(h.z, f0.z, f1.z, f2.z, g0.z, g1.z, g2.z, g3.z);                      \
    PIX1(h.w, f0.w, f1.w, f2.w, g0.w, g1.w, g2.w, g3.w)

    STREAM_LOOP(PIXSET1_);

    __syncthreads();                     // DMA fully drained (last VMWAIT0)
#define REDS(i_, var_) { float r_ = waveReduce64(var_); if (lane == 0) shred[wav][i_] = r_; }
    REDS(0, cnt);
    REDS(1, s0_0); REDS(2, s0_1); REDS(3, s0_2); REDS(4, s0_3);
    REDS(5, u00); REDS(6, u01); REDS(7, u02);
    REDS(8, u10); REDS(9, u11); REDS(10, u12);
    REDS(11, u20); REDS(12, u21); REDS(13, u22);
    REDS(14, u30); REDS(15, u31); REDS(16, u32);
    REDS(17, q00); REDS(18, q01); REDS(19, q02);
    REDS(20, q10); REDS(21, q11); REDS(22, q12);
    REDS(23, q20); REDS(24, q21); REDS(25, q22);
    REDS(26, q30); REDS(27, q31); REDS(28, q32);
#undef REDS
    __syncthreads();
    if (tid < 29) {
        float v = shred[0][tid] + shred[1][tid] + shred[2][tid] + shred[3][tid];
        float* p1 = reinterpret_cast<float*>(wsraw + P1OFF);
        p1[(((size_t)b * G1 + g) << 5) + tid] = v;
    }
}

// ---------------------------------------------------------------------------
// Batch totals, computed ONCE per batch (f64).
// ---------------------------------------------------------------------------
__global__ __launch_bounds__(256) void reduce_totals(char* __restrict__ wsraw) {
    const int b   = blockIdx.x;
    const int tid = threadIdx.x;
    const float* p1 = reinterpret_cast<const float*>(wsraw + P1OFF) + ((size_t)b * G1 << 5);
    __shared__ double red[8][32];
    const int col = tid & 31, r = tid >> 5;
    double s = 0.0;
    if (col < 29) {
#pragma unroll
        for (int j = r; j < G1; j += 8) s += (double)p1[((size_t)j << 5) + col];
    }
    red[r][col] = s;
    __syncthreads();
    if (tid < 29) {
        double t = 0.0;
#pragma unroll
        for (int r2 = 0; r2 < 8; ++r2) t += red[r2][tid];
        reinterpret_cast<double*>(wsraw)[(size_t)b * 32 + tid] = t;
    }
}

// ---------------------------------------------------------------------------
// Pass 2: same streaming skeleton; params in SGPRs; loglik accumulate.
// ---------------------------------------------------------------------------
__global__ __launch_bounds__(256) void pass2_loglik(
        const float* __restrict__ predictions,
        const float* __restrict__ inputs,
        const int*   __restrict__ heart,
        char*        __restrict__ wsraw) {
    const int b    = blockIdx.y;
    const int g    = blockIdx.x;
    const int tid  = threadIdx.x;
    const int lane = tid & 63;
    const int wav  = tid >> 6;

    __shared__ __align__(16) char lds[2 * BUFB];
    __shared__ float shred2[4];

    const double* tot = reinterpret_cast<const double*>(wsraw) + (size_t)b * 32;

    float mu00, mu01, mu02, mu10, mu11, mu12, mu20, mu21, mu22, mu30, mu31, mu32;
    float hv00, hv01, hv02, hv10, hv11, hv12, hv20, hv21, hv22, hv30, hv31, hv32;
    float C0, C1, C2, C3;
    PARAMK(0, mu00, mu01, mu02, hv00, hv01, hv02, C0);
    PARAMK(1, mu10, mu11, mu12, hv10, hv11, hv12, C1);
    PARAMK(2, mu20, mu21, mu22, hv20, hv21, hv22, C2);
    PARAMK(3, mu30, mu31, mu32, hv30, hv31, hv32, C3);
    mu00=rfl(mu00); mu01=rfl(mu01); mu02=rfl(mu02);
    mu10=rfl(mu10); mu11=rfl(mu11); mu12=rfl(mu12);
    mu20=rfl(mu20); mu21=rfl(mu21); mu22=rfl(mu22);
    mu30=rfl(mu30); mu31=rfl(mu31); mu32=rfl(mu32);
    hv00=rfl(hv00); hv01=rfl(hv01); hv02=rfl(hv02);
    hv10=rfl(hv10); hv11=rfl(hv11); hv12=rfl(hv12);
    hv20=rfl(hv20); hv21=rfl(hv21); hv22=rfl(hv22);
    hv30=rfl(hv30); hv31=rfl(hv31); hv32=rfl(hv32);
    C0=rfl(C0); C1=rfl(C1); C2=rfl(C2); C3=rfl(C3);

    DECL_GSRC;

    float lacc = 0.f;

#define PIXSET2_                                                              \
    PIX2(h.x, f0.x, f1.x, f2.x, g0.x, g1.x, g2.x, g3.x);                      \
    PIX2(h.y, f0.y, f1.y, f2.y, g0.y, g1.y, g2.y, g3.y);                      \
    PIX2(h.z, f0.z, f1.z, f2.z, g0.z, g1.z, g2.z, g3.z);                      \
    PIX2(h.w, f0.w, f1.w, f2.w, g0.w, g1.w, g2.w, g3.w)

    STREAM_LOOP(PIXSET2_);

    __syncthreads();
    {
        float v = waveReduce64(lacc);
        if (lane == 0) shred2[wav] = v;
    }
    __syncthreads();
    if (tid == 0) {
        float* p2 = reinterpret_cast<float*>(wsraw + P2OFF);
        p2[(size_t)b * G1 + g] = shred2[0] + shred2[1] + shred2[2] + shred2[3];
    }
}

// ---------------------------------------------------------------------------
// Finalize: per-batch loglik sum / mask count, mean over batches.
// ---------------------------------------------------------------------------
__global__ __launch_bounds__(256) void finalize_kernel(
        const char* __restrict__ wsraw, float* __restrict__ out) {
    const float*  p2  = reinterpret_cast<const float*>(wsraw + P2OFF);
    const double* tot = reinterpret_cast<const double*>(wsraw);
    __shared__ double red[16][17];
    const int tid = threadIdx.x;          // 256 threads: 16 batches x 16 lanes
    const int b = tid >> 4, r = tid & 15;
    double s = 0.0;
#pragma unroll
    for (int j = r; j < G1; j += 16)
        s += (double)p2[(size_t)b * G1 + j];
    red[b][r] = s;
    __syncthreads();
    double v = 0.0;
    if (tid < NB) {
        double l = 0.0;
#pragma unroll
        for (int r2 = 0; r2 < 16; ++r2) l += red[tid][r2];
        v = -l / tot[(size_t)tid * 32];   // tot[b][0] = mask count
    }
#pragma unroll
    for (int off = 8; off > 0; off >>= 1) v += __shfl_down(v, off, 64);
    if (tid == 0) out[0] = (float)(v / (double)NB);
}

extern "C" void kernel_launch(void* const* d_in, const int* in_sizes, int n_in,
                              void* d_out, int out_size, void* d_ws, size_t ws_size,
                              hipStream_t stream) {
    const float* predictions = (const float*)d_in[0];
    const float* inputs      = (const float*)d_in[1];
    const int*   heart       = (const int*)d_in[2];
    float* out   = (float*)d_out;
    char*  wsraw = (char*)d_ws;

    pass1_moments<<<dim3(G1, NB), 256, 0, stream>>>(predictions, inputs, heart, wsraw);
    reduce_totals<<<dim3(NB),     256, 0, stream>>>(wsraw);
    pass2_loglik <<<dim3(G1, NB), 256, 0, stream>>>(predictions, inputs, heart, wsraw);
    finalize_kernel<<<1,          256, 0, stream>>>(wsraw, out);
}